// Round 7
// baseline (1122.858 us; speedup 1.0000x reference)
//
#include <hip/hip_runtime.h>
#include <cstdint>
#include <math.h>

// ---------------- problem constants ----------------
static constexpr int NB  = 8;
static constexpr int CC_ = 256;          // channels
static constexpr int HH  = 100, WW = 100, HW = 10000;
static constexpr int KA  = 9;
static constexpr int AN  = HW * KA;      // 90000 anchors/image
static constexpr int PRE  = 3000;
static constexpr int POST = 300;
static constexpr int NW64 = 47;          // ceil(3000/64)
static constexpr float NMS_T = 0.7f;

typedef _Float16 f16;
typedef _Float16 f16x8 __attribute__((ext_vector_type(8)));
typedef float f32x4 __attribute__((ext_vector_type(4)));

// d_out layout (float offsets)
static constexpr size_t OUT_CLS  = 0;            // 8*2*90000 = 1,440,000
static constexpr size_t OUT_REG  = 1440000;      // 8*90000*4 = 2,880,000
static constexpr size_t OUT_ROIS = 4320000;      // 2400*4
static constexpr size_t OUT_RIND = 4329600;      // 2400
static constexpr size_t OUT_ANCH = 4332000;      // 90000*4

// workspace layout (byte offsets, all 16B-aligned)
// WS_WT region holds WH (1,179,648) + WL (1,179,648): split-f16 weights in
// A-fragment order [tap9][kg8][kq4][co256][8ci].
static constexpr size_t WS_H     = 0;                          // 81,920,000
static constexpr size_t WS_WT    = 81920000;                   //  2,359,296
static constexpr size_t WS_W54   = WS_WT   + 2359296;          //     55,296
static constexpr size_t WS_BOXES = WS_W54  + 55296;            // 11,520,000
static constexpr size_t WS_KEYS  = WS_BOXES+ 11520000;         //  2,880,000
static constexpr size_t WS_SBOX  = WS_KEYS + 2880000;          //    384,000
static constexpr size_t WS_SVAL  = WS_SBOX + 384000;           //     96,000
static constexpr size_t WS_MASK  = WS_SVAL + 96000;            //  9,048,064
// R15: selection scratch ALIASES the first 328KB of the mask region — selection
// kernels all run BEFORE k_mask writes it. Zeroed each launch by k_prep_all.
static constexpr size_t SEL_H1   = 0;        // bytes from WS_MASK: 8x1024 u32 = 32768
static constexpr size_t SEL_H2   = 32768;    // 32768
static constexpr size_t SEL_META = 65536;    // 8x4 i32 (B1,A1,B2,cnt) + pad = 256
static constexpr size_t SEL_CAND = 65792;    // 8x4096 u64 = 262144
static constexpr int    SEL_ZERO_U32 = 81984;  // total u32 to zero (hist1+hist2+meta+cand)

// anchor heights/widths per k = r_idx*3 + s_idx  (fp32 of f64-exact values)
__device__ __constant__ float AHC[9] = {
  90.50966799187809f, 181.01933598375618f, 362.03867196751236f,
  128.f, 256.f, 512.f,
  181.01933598375618f, 362.03867196751236f, 724.0773439350247f };
__device__ __constant__ float AWC[9] = {
  181.01933598375618f, 362.03867196751236f, 724.0773439350247f,
  128.f, 256.f, 512.f,
  90.50966799187809f, 181.01933598375618f, 362.03867196751236f };

// ---------------- prep: split-f16 weights + head weights + anchors + sel-scratch zero ----
__global__ void k_prep_all(const float* __restrict__ w1, const float* __restrict__ wc,
                           const float* __restrict__ wr, f16* __restrict__ WH,
                           f16* __restrict__ WL, float* __restrict__ w54,
                           float* __restrict__ anch, unsigned* __restrict__ selz) {
  int t = blockIdx.x * 256 + threadIdx.x;
  if (t < SEL_ZERO_U32) selz[t] = 0u;
  if (t < 589824) {
    // t = (((tap*8 + kg)*4 + kq)*256 + co)*8 + cil ; ci = kg*32 + kq*8 + cil
    int cil = t & 7, co = (t >> 3) & 255, rr = t >> 11;
    int kq = rr & 3, kg = (rr >> 2) & 7, tap = rr >> 5;
    int ci = kg * 32 + kq * 8 + cil;
    float v = w1[((size_t)co * 256 + ci) * 9 + tap];
    f16 hi = (f16)v;
    float res = v - (float)hi;
    WH[t] = hi;
    WL[t] = (f16)(res * 2048.f);     // scaled-lo: exact pow2 scale, avoids f16 denorm loss
  }
  if (t < 256 * 54) {
    int ci = t / 54, j = t % 54;
    w54[t] = (j < 18) ? wc[j * 256 + ci] : wr[(j - 18) * 256 + ci];
  }
  int u = t - 256 * 54;
  if (u >= 0 && u < AN) {
    int k = u % KA; int pp = u / KA; int y = pp / WW; int x = pp % WW;
    int ri = k / 3, si = k % 3;
    double scale = (double)(8 << si);
    double r = (ri == 0) ? 0.5 : ((ri == 1) ? 1.0 : 2.0);
    double hh = 16.0 * scale * sqrt(r);
    double ww = 16.0 * scale * sqrt(1.0 / r);
    double sy = y * 16.0, sx = x * 16.0;
    anch[(size_t)u * 4 + 0] = (float)(sy + 8.0 - hh * 0.5);
    anch[(size_t)u * 4 + 1] = (float)(sx + 8.0 - ww * 0.5);
    anch[(size_t)u * 4 + 2] = (float)(sy + 8.0 + hh * 0.5);
    anch[(size_t)u * 4 + 3] = (float)(sx + 8.0 + ww * 0.5);
  }
}

// ---------------- conv 3x3 pad 1 + bias + relu — split-f16 MFMA implicit GEMM ----------------
// R14 structure UNCHANGED in R15 (415us, MfmaUtil 35.5%): sched_barrier-pinned
// A ping-pong + kx-major 6-row B cache. See R14 notes. Bit-exact preserved.
__global__ __launch_bounds__(256, 3) void k_conv3x3(const float* __restrict__ x,
    const f16* __restrict__ WH, const f16* __restrict__ WL,
    const float* __restrict__ b1, float* __restrict__ hout) {
  __shared__ __align__(16) f16 SX[2][2][4][180][8];   // [buf][hl][kq][pix][8ci]
  const int tid = threadIdx.x;
  const int lane = tid & 63;
  const int w = tid >> 6;
  // XCD-colocating decode (bijective: 728 pixel-regions x 4 co-tiles = 2912)
  const int bid = blockIdx.x;
  const int p = ((bid >> 5) << 3) | (bid & 7);   // pixel-region 0..727
  const int cotile = (bid >> 3) & 3;             // 0..3
  const int xt_yt = p % 91;
  const int n = p / 91;
  const int xt = xt_yt % 7, yt = xt_yt / 7;
  const int x0 = xt * 16, y0 = yt * 8;
  const int wy = (w & 1) * 4;         // wave's 4-row strip within 8-row tile
  const int wc = (w >> 1) * 32;       // wave's 32-co slice within 64
  const int xb = lane & 15, kh = lane >> 4;

  // staging: threads 0..179 each own one (r,c) of the 10x18 halo tile
  const int sp = tid;
  const bool s_on = sp < 180;
  const int s_r = sp / 18, s_c = sp % 18;
  const int gy = y0 - 1 + s_r, gx = x0 - 1 + s_c;
  const bool s_ok = s_on && gy >= 0 && gy < HH && gx >= 0 && gx < WW;
  const int s_goff = s_ok ? gy * WW + gx : 0;

  const float* xn = x + (size_t)n * CC_ * HW;

  f32x4 acc1[2][4], acc2[2][4];
  #pragma unroll
  for (int a = 0; a < 2; ++a)
    #pragma unroll
    for (int b = 0; b < 4; ++b) {
      acc1[a][b] = (f32x4){0.f, 0.f, 0.f, 0.f};
      acc2[a][b] = (f32x4){0.f, 0.f, 0.f, 0.f};
    }

  float xv[16];
  auto prefetch16 = [&](int kg2, int half) {
    if (s_ok) {
      const float* bp = xn + (size_t)(kg2 * 32 + half * 16) * HW + s_goff;
      #pragma unroll
      for (int j = 0; j < 16; ++j) xv[j] = bp[(size_t)j * HW];
    } else {
      #pragma unroll
      for (int j = 0; j < 16; ++j) xv[j] = 0.f;
    }
  };
  auto commit16 = [&](int nb, int half) {
    if (s_on) {
      #pragma unroll
      for (int q = 0; q < 2; ++q) {
        f16x8 H, L;
        #pragma unroll
        for (int j = 0; j < 8; ++j) {
          float v = xv[q * 8 + j];
          f16 hi = (f16)v;
          float res = v - (float)hi;
          H[j] = hi;
          L[j] = (f16)(res * 2048.f);
        }
        *(f16x8*)&SX[nb][0][half * 2 + q][sp][0] = H;
        *(f16x8*)&SX[nb][1][half * 2 + q][sp][0] = L;
      }
    }
  };

  const int cob = cotile * 64 + wc;
  auto loadA = [&](int kg2, int tap, f16x8* ah, f16x8* al) {
    const size_t wbase = ((((size_t)tap * 8 + kg2) * 4 + kh) * 256 + cob + xb) * 8;
    #pragma unroll
    for (int cf = 0; cf < 2; ++cf) {
      ah[cf] = *(const f16x8*)(WH + wbase + (size_t)cf * 128);  // +16 co
      al[cf] = *(const f16x8*)(WL + wbase + (size_t)cf * 128);
    }
  };

  // prologue: stage ci-group 0 (both halves)
  prefetch16(0, 0); commit16(0, 0);
  prefetch16(0, 1); commit16(0, 1);
  __syncthreads();

  for (int kg = 0; kg < 8; ++kg) {
    const int buf = kg & 1;
    const bool more = (kg < 7);
    f16x8 ah[2][2], al[2][2];           // [pingpong][cf] — static idx (unrolled)
    loadA(kg, 0, ah[0], al[0]);         // s=0 is (kx0,ky0) -> tap 0
    if (more) prefetch16(kg + 1, 0);    // issue early: hides under kx=0..1 MFMAs
    __builtin_amdgcn_sched_barrier(0);  // pin: loads issued before any MFMA below
    #pragma unroll
    for (int kx = 0; kx < 3; ++kx) {
      // 6-row B cache for this kx (rows wy..wy+5 cover all ky windows)
      f16x8 rh[6], rl[6];
      #pragma unroll
      for (int r = 0; r < 6; ++r) {
        const int pixf = (wy + r) * 18 + xb + kx;
        rh[r] = *(const f16x8*)&SX[buf][0][kh][pixf][0];
        rl[r] = *(const f16x8*)&SX[buf][1][kh][pixf][0];
      }
      #pragma unroll
      for (int ky = 0; ky < 3; ++ky) {
        const int s = kx * 3 + ky;       // processing order
        const int cur = s & 1;
        if (s < 8) {                     // A ping-pong: issue next tap's frags
          const int s2 = s + 1;
          loadA(kg, (s2 % 3) * 3 + s2 / 3, ah[cur ^ 1], al[cur ^ 1]);
        }
        __builtin_amdgcn_sched_barrier(0);  // pin: next-A issued before this MFMA pack
        #pragma unroll
        for (int cf = 0; cf < 2; ++cf)
          #pragma unroll
          for (int nf = 0; nf < 4; ++nf) {
            acc1[cf][nf] = __builtin_amdgcn_mfma_f32_16x16x32_f16(ah[cur][cf], rh[nf + ky], acc1[cf][nf], 0, 0, 0);
            acc2[cf][nf] = __builtin_amdgcn_mfma_f32_16x16x32_f16(ah[cur][cf], rl[nf + ky], acc2[cf][nf], 0, 0, 0);
            acc2[cf][nf] = __builtin_amdgcn_mfma_f32_16x16x32_f16(al[cur][cf], rh[nf + ky], acc2[cf][nf], 0, 0, 0);
          }
      }
      if (kx == 1 && more) {
        commit16(buf ^ 1, 0);            // write-late (xv landed ~2 kx blocks ago)
        prefetch16(kg + 1, 1);           // issue 2nd half; hides under kx=2
        __builtin_amdgcn_sched_barrier(0);
      }
    }
    if (more) commit16(buf ^ 1, 1);
    __syncthreads();
  }

  // epilogue: combine, bias, relu, store (C/D: col=lane&15=x, row=kh*4+reg=co)
  const int xg = x0 + xb;
  #pragma unroll
  for (int cf = 0; cf < 2; ++cf)
    #pragma unroll
    for (int r = 0; r < 4; ++r) {
      const int co = cob + cf * 16 + kh * 4 + r;
      const float bias = b1[co];
      const size_t obase = (size_t)(n * CC_ + co) * HH;
      #pragma unroll
      for (int nf = 0; nf < 4; ++nf) {
        const int yg = y0 + wy + nf;
        if (yg < HH && xg < WW) {
          float v = fmaf(acc2[cf][nf][r], 0.00048828125f, acc1[cf][nf][r]) + bias;
          hout[(obase + yg) * WW + xg] = fmaxf(v, 0.f);
        }
      }
    }
}

// ---------------- 1x1 heads + decode + score keys ----------------
__global__ __launch_bounds__(256) void k_heads(const float* __restrict__ hin,
    const float* __restrict__ w54, const float* __restrict__ bc, const float* __restrict__ br,
    const int* __restrict__ imw, const int* __restrict__ imh,
    float* __restrict__ cls_out, float* __restrict__ reg_out,
    float* __restrict__ boxes, unsigned int* __restrict__ keys) {
  int gid = blockIdx.x * 256 + threadIdx.x;
  if (gid >= NB * HW) return;
  int n = gid / HW, p = gid % HW;
  float cacc[18], racc[36];
  #pragma unroll
  for (int j = 0; j < 18; ++j) cacc[j] = 0.f;
  #pragma unroll
  for (int j = 0; j < 36; ++j) racc[j] = 0.f;
  const float* hp = hin + (size_t)n * CC_ * HW + p;
  #pragma unroll 8
  for (int ci = 0; ci < CC_; ++ci) {
    float hv = hp[(size_t)ci * HW];
    const float* wrow = w54 + ci * 54;
    #pragma unroll
    for (int j = 0; j < 18; ++j) cacc[j] = fmaf(hv, wrow[j], cacc[j]);
    #pragma unroll
    for (int j = 0; j < 36; ++j) racc[j] = fmaf(hv, wrow[18 + j], racc[j]);
  }
  const float imgW = (float)imw[0], imgH = (float)imh[0];
  const int y = p / WW, xq = p % WW;
  #pragma unroll
  for (int k = 0; k < 9; ++k) {
    float c0 = cacc[2 * k] + bc[2 * k];
    float c1 = cacc[2 * k + 1] + bc[2 * k + 1];
    int a = p * 9 + k;
    cls_out[(size_t)n * 2 * AN + a]      = c0;
    cls_out[(size_t)n * 2 * AN + AN + a] = c1;
    float t0 = racc[4 * k]     + br[4 * k];
    float t1 = racc[4 * k + 1] + br[4 * k + 1];
    float t2 = racc[4 * k + 2] + br[4 * k + 2];
    float t3 = racc[4 * k + 3] + br[4 * k + 3];
    size_t ro = ((size_t)n * AN + a) * 4;
    reg_out[ro] = t0; reg_out[ro + 1] = t1; reg_out[ro + 2] = t2; reg_out[ro + 3] = t3;
    float hk = AHC[k], wk = AWC[k];
    float cy = fmaf(t0, hk, y  * 16.f + 8.f);
    float cx = fmaf(t1, wk, xq * 16.f + 8.f);
    float bh = expf(t2) * hk, bw = expf(t3) * wk;
    float y1 = cy - 0.5f * bh, x1 = cx - 0.5f * bw;
    float y2 = cy + 0.5f * bh, x2 = cx + 0.5f * bw;
    y1 = fminf(fmaxf(y1, 0.f), imgH); y2 = fminf(fmaxf(y2, 0.f), imgH);
    x1 = fminf(fmaxf(x1, 0.f), imgW); x2 = fminf(fmaxf(x2, 0.f), imgW);
    bool valid = (y2 - y1 >= 16.f) && (x2 - x1 >= 16.f);
    boxes[ro] = y1; boxes[ro + 1] = x1; boxes[ro + 2] = y2; boxes[ro + 3] = x2;
    float dc = c1 - c0;                       // monotone in softmax fg
    unsigned u = __float_as_uint(dc);
    u = (u & 0x80000000u) ? ~u : (u | 0x80000000u);
    keys[(size_t)n * AN + a] = valid ? u : 0u;
  }
}

// ---------------- R15: grid-parallel top-3000 selection (semantics == old k_select) --------
// Phase A: per-image histogram of key>>22 (32 blocks/image, 4-replica LDS + global atomic)
__global__ __launch_bounds__(256) void k_sel_hist1(const unsigned* __restrict__ keys,
    unsigned* __restrict__ hist1) {
  __shared__ unsigned h[4][1024];
  const int t = threadIdx.x, n = blockIdx.y;
  for (int i = t; i < 4096; i += 256) ((unsigned*)h)[i] = 0;
  __syncthreads();
  const unsigned* kp = keys + (size_t)n * AN;
  const int wv = t >> 6;
  for (int i = blockIdx.x * 256 + t; i < AN; i += 32 * 256)
    atomicAdd(&h[wv][kp[i] >> 22], 1u);
  __syncthreads();
  for (int b = t; b < 1024; b += 256) {
    unsigned s = h[0][b] + h[1][b] + h[2][b] + h[3][b];
    if (s) atomicAdd(&hist1[n * 1024 + b], s);
  }
}

// Phase B: suffix-scan hist1 -> B1, A1 (exact copy of old scan logic)
__global__ __launch_bounds__(1024) void k_sel_thresh1(const unsigned* __restrict__ hist1,
    int* __restrict__ meta) {
  __shared__ unsigned sc[1024];
  __shared__ int sB1, sA1;
  const int t = threadIdx.x, n = blockIdx.x;
  unsigned myc = hist1[n * 1024 + t];
  sc[t] = myc;
  __syncthreads();
  for (int off = 1; off < 1024; off <<= 1) {
    unsigned add = (t + off < 1024) ? sc[t + off] : 0;
    __syncthreads();
    sc[t] += add;
    __syncthreads();
  }
  unsigned incl = sc[t];
  unsigned above = incl - myc;
  if (above < (unsigned)PRE && incl >= (unsigned)PRE && myc > 0) { sB1 = t; sA1 = (int)above; }
  __syncthreads();
  if (t == 0) { meta[n * 4 + 0] = sB1; meta[n * 4 + 1] = sA1; }
}

// Phase C: histogram of (key>>12)&1023 restricted to bucket B1
__global__ __launch_bounds__(256) void k_sel_hist2(const unsigned* __restrict__ keys,
    const int* __restrict__ meta, unsigned* __restrict__ hist2) {
  __shared__ unsigned h[4][1024];
  __shared__ int sB1;
  const int t = threadIdx.x, n = blockIdx.y;
  if (t == 0) sB1 = meta[n * 4 + 0];
  for (int i = t; i < 4096; i += 256) ((unsigned*)h)[i] = 0;
  __syncthreads();
  const int B1 = sB1;
  const unsigned* kp = keys + (size_t)n * AN;
  const int wv = t >> 6;
  for (int i = blockIdx.x * 256 + t; i < AN; i += 32 * 256) {
    unsigned k32 = kp[i];
    if ((int)(k32 >> 22) == B1) atomicAdd(&h[wv][(k32 >> 12) & 1023u], 1u);
  }
  __syncthreads();
  for (int b = t; b < 1024; b += 256) {
    unsigned s = h[0][b] + h[1][b] + h[2][b] + h[3][b];
    if (s) atomicAdd(&hist2[n * 1024 + b], s);
  }
}

// Phase D: suffix-scan hist2 -> B2
__global__ __launch_bounds__(1024) void k_sel_thresh2(const unsigned* __restrict__ hist2,
    int* __restrict__ meta) {
  __shared__ unsigned sc[1024];
  __shared__ int sB2;
  const int t = threadIdx.x, n = blockIdx.x;
  unsigned myc = hist2[n * 1024 + t];
  sc[t] = myc;
  __syncthreads();
  for (int off = 1; off < 1024; off <<= 1) {
    unsigned add = (t + off < 1024) ? sc[t + off] : 0;
    __syncthreads();
    sc[t] += add;
    __syncthreads();
  }
  unsigned incl = sc[t];
  unsigned above = incl - myc;
  const int target = PRE - meta[n * 4 + 1];
  if ((int)above < target && (int)incl >= target && myc > 0) sB2 = t;
  __syncthreads();
  if (t == 0) meta[n * 4 + 2] = sB2;
}

// Phase E: compact candidates (same predicate, same 4096 cap, same payload)
__global__ __launch_bounds__(256) void k_sel_compact(const unsigned* __restrict__ keys,
    int* __restrict__ meta, unsigned long long* __restrict__ cand) {
  __shared__ int sB1, sB2;
  const int t = threadIdx.x, n = blockIdx.y;
  if (t == 0) { sB1 = meta[n * 4 + 0]; sB2 = meta[n * 4 + 2]; }
  __syncthreads();
  const int B1 = sB1, B2 = sB2;
  const unsigned* kp = keys + (size_t)n * AN;
  for (int i = blockIdx.x * 256 + t; i < AN; i += 32 * 256) {
    unsigned k32 = kp[i];
    int b1 = (int)(k32 >> 22);
    bool sel = (b1 > B1) || (b1 == B1 && (int)((k32 >> 12) & 1023u) >= B2);
    if (sel) {
      int pos = atomicAdd(&meta[n * 4 + 3], 1);
      if (pos < 4096)
        cand[(size_t)n * 4096 + pos] =
          ((unsigned long long)k32 << 32) | (unsigned long long)(0xFFFFFFFFu - (unsigned)i);
    }
  }
}

// Phase F: per-image bitonic sort of 4096 (identical to old) + emit sbox/sval
__global__ __launch_bounds__(1024) void k_sel_sort(const unsigned long long* __restrict__ candg,
    const float* __restrict__ boxes, float* __restrict__ sbox, int* __restrict__ sval) {
  __shared__ unsigned long long cand[4096];
  const int t = threadIdx.x, n = blockIdx.x;
  for (int i = t; i < 4096; i += 1024) cand[i] = candg[(size_t)n * 4096 + i];
  __syncthreads();
  for (int k = 2; k <= 4096; k <<= 1) {
    for (int j = k >> 1; j > 0; j >>= 1) {
      for (int i = t; i < 4096; i += 1024) {
        int ixj = i ^ j;
        if (ixj > i) {
          unsigned long long va = cand[i], vb = cand[ixj];
          bool desc = ((i & k) == 0);
          if (desc ? (va < vb) : (va > vb)) { cand[i] = vb; cand[ixj] = va; }
        }
      }
      __syncthreads();
    }
  }
  for (int i = t; i < PRE; i += 1024) {
    unsigned long long kv = cand[i];
    unsigned idx = 0xFFFFFFFFu - (unsigned)(kv & 0xFFFFFFFFull);
    float4 bb = *(const float4*)(boxes + ((size_t)n * AN + idx) * 4);
    *(float4*)(sbox + ((size_t)n * PRE + i) * 4) = bb;
    sval[n * PRE + i] = ((kv >> 32) != 0ull) ? 1 : 0;
  }
}

// ---------------- NMS suppression bitmask: 4 i-tiles per 256-thread block ----------------
__global__ __launch_bounds__(256) void k_mask(const float* __restrict__ sbox,
    unsigned long long* __restrict__ mask) {
  __shared__ float4 jb[64];
  const int t = threadIdx.x;
  const int lane = t & 63, wv = t >> 6;
  const int jt = blockIdx.x, n = blockIdx.z;
  const int it = blockIdx.y * 4 + wv;
  const int j0 = jt * 64;
  if (t < 64) {
    int jg = j0 + t;
    float4 v = make_float4(0.f, 0.f, 0.f, 0.f);
    if (jg < PRE) v = *(const float4*)(sbox + ((size_t)n * PRE + jg) * 4);
    jb[t] = v;
  }
  __syncthreads();
  const int i = it * 64 + lane;
  if (it >= NW64 || i >= PRE) return;
  float4 bi = *(const float4*)(sbox + ((size_t)n * PRE + i) * 4);
  float areaI = (bi.z - bi.x) * (bi.w - bi.y);
  unsigned long long bits = 0ull;
  #pragma unroll 4
  for (int jj = 0; jj < 64; ++jj) {
    int j = j0 + jj;
    float4 bj = jb[jj];
    float yy1 = fmaxf(bi.x, bj.x), xx1 = fmaxf(bi.y, bj.y);
    float yy2 = fminf(bi.z, bj.z), xx2 = fminf(bi.w, bj.w);
    float inter = fmaxf(yy2 - yy1, 0.f) * fmaxf(xx2 - xx1, 0.f);
    float areaJ = (bj.z - bj.x) * (bj.w - bj.y);
    float iou = inter / (areaI + areaJ - inter + 1e-9f);
    if (iou > NMS_T && j > i && j < PRE) bits |= (1ull << jj);
  }
  mask[((size_t)n * 3008 + i) * NW64 + jt] = bits;
}

// ---------------- fused: sequential greedy NMS scan + rank-compact top-300 ----------------
__global__ __launch_bounds__(256) void k_nms_final(const unsigned long long* __restrict__ mask,
    const int* __restrict__ sval, const float* __restrict__ sbox,
    float* __restrict__ rois, float* __restrict__ rind) {
  __shared__ unsigned long long kws[NW64];
  __shared__ int pref[NW64 + 1];
  const int t = threadIdx.x, n = blockIdx.x;
  // phase 1: wave 0 does the serial greedy scan (identical semantics to k_nms_seq)
  if (t < 64) {
    unsigned long long keep = 0ull;
    for (int w = 0; w < NW64; ++w) {
      int i = w * 64 + t;
      int v = (i < PRE) ? sval[n * PRE + i] : 0;
      unsigned long long m = __ballot(v != 0);
      if (t == w) keep = m;     // in-register, no LDS round-trip needed (single wave)
    }
    const unsigned long long* mrow = mask + (size_t)n * 3008 * NW64;
    unsigned long long buf[16];
    #pragma unroll
    for (int r = 0; r < 16; ++r)
      buf[r] = (t < NW64) ? mrow[(size_t)r * NW64 + t] : 0ull;
    for (int base = 0; base < PRE; base += 16) {
      #pragma unroll
      for (int r = 0; r < 16; ++r) {
        int i = base + r;
        if (i < PRE) {
          unsigned long long kb = __shfl(keep, i >> 6);
          if ((kb >> (i & 63)) & 1ull) keep &= ~buf[r];
        }
        int nx = i + 16;
        buf[r] = (nx < PRE && t < NW64) ? mrow[(size_t)nx * NW64 + t] : 0ull;
      }
    }
    if (t < NW64) kws[t] = keep;
  }
  __syncthreads();
  // phase 2: all threads — identical to k_final
  if (t == 0) {
    int s = 0;
    for (int w = 0; w < NW64; ++w) { pref[w] = s; s += __popcll(kws[w]); }
    pref[NW64] = s;
  }
  for (int e = t; e < POST * 4; e += 256) rois[(size_t)n * POST * 4 + e] = 0.f;
  for (int e = t; e < POST; e += 256) rind[(size_t)n * POST + e] = (float)n;
  __syncthreads();
  for (int i = t; i < PRE; i += 256) {
    int wd = i >> 6, b = i & 63;
    unsigned long long wv = kws[wd];
    if ((wv >> b) & 1ull) {
      int rank = pref[wd] + __popcll(wv & ((1ull << b) - 1ull));
      if (rank < POST) {
        float4 bb = *(const float4*)(sbox + ((size_t)n * PRE + i) * 4);
        *(float4*)(rois + ((size_t)n * POST + rank) * 4) = bb;
      }
    }
  }
}

// ---------------- launch (11 kernels total) ----------------
extern "C" void kernel_launch(void* const* d_in, const int* in_sizes, int n_in,
                              void* d_out, int out_size, void* d_ws, size_t ws_size,
                              hipStream_t stream) {
  const float* x  = (const float*)d_in[0];
  const float* w1 = (const float*)d_in[1];
  const float* b1 = (const float*)d_in[2];
  const float* wc = (const float*)d_in[3];
  const float* bc = (const float*)d_in[4];
  const float* wr = (const float*)d_in[5];
  const float* br = (const float*)d_in[6];
  const int* imw  = (const int*)d_in[7];
  const int* imh  = (const int*)d_in[8];
  float* out = (float*)d_out;
  char* ws = (char*)d_ws;
  float* hbuf = (float*)(ws + WS_H);
  f16* WH     = (f16*)(ws + WS_WT);
  f16* WL     = (f16*)(ws + WS_WT + 1179648);
  float* w54  = (float*)(ws + WS_W54);
  float* boxes = (float*)(ws + WS_BOXES);
  unsigned* keys = (unsigned*)(ws + WS_KEYS);
  float* sbox = (float*)(ws + WS_SBOX);
  int* sval   = (int*)(ws + WS_SVAL);
  unsigned long long* mask  = (unsigned long long*)(ws + WS_MASK);
  // selection scratch aliases the head of the mask region (used strictly before k_mask)
  unsigned* sel_h1 = (unsigned*)(ws + WS_MASK + SEL_H1);
  unsigned* sel_h2 = (unsigned*)(ws + WS_MASK + SEL_H2);
  int* sel_meta    = (int*)(ws + WS_MASK + SEL_META);
  unsigned long long* sel_cand = (unsigned long long*)(ws + WS_MASK + SEL_CAND);

  k_prep_all<<<2304, 256, 0, stream>>>(w1, wc, wr, WH, WL, w54, out + OUT_ANCH, sel_h1);
  k_conv3x3<<<2912, 256, 0, stream>>>(x, WH, WL, b1, hbuf);
  k_heads<<<313, 256, 0, stream>>>(hbuf, w54, bc, br, imw, imh,
                                   out + OUT_CLS, out + OUT_REG, boxes, keys);
  k_sel_hist1<<<dim3(32, NB), 256, 0, stream>>>(keys, sel_h1);
  k_sel_thresh1<<<NB, 1024, 0, stream>>>(sel_h1, sel_meta);
  k_sel_hist2<<<dim3(32, NB), 256, 0, stream>>>(keys, sel_meta, sel_h2);
  k_sel_thresh2<<<NB, 1024, 0, stream>>>(sel_h2, sel_meta);
  k_sel_compact<<<dim3(32, NB), 256, 0, stream>>>(keys, sel_meta, sel_cand);
  k_sel_sort<<<NB, 1024, 0, stream>>>(sel_cand, boxes, sbox, sval);
  k_mask<<<dim3(NW64, 12, NB), 256, 0, stream>>>(sbox, mask);
  k_nms_final<<<NB, 256, 0, stream>>>(mask, sval, sbox, out + OUT_ROIS, out + OUT_RIND);
}